// Round 1
// baseline (2445.279 us; speedup 1.0000x reference)
//
#include <hip/hip_runtime.h>
#include <hip/hip_bf16.h>
#include <math.h>

#define NNODES 50000
#define NEDGES 800000
#define NGRAPHS 128

// ---------------------------------------------------------------- CSR build
__global__ void count_edges(const int* __restrict__ ei, int* __restrict__ cnt) {
    int e = blockIdx.x * 256 + threadIdx.x;
    if (e < NEDGES) atomicAdd(&cnt[ei[NEDGES + e]], 1);
}

__global__ void scan_counts(const int* __restrict__ cnt, int* __restrict__ rowptr,
                            int* __restrict__ wpos) {
    __shared__ int part[256];
    const int t = threadIdx.x;
    const int CHK = (NNODES + 255) / 256;     // 196
    int lo = t * CHK, hi = min(lo + CHK, NNODES);
    int s = 0;
    for (int i = lo; i < hi; ++i) s += cnt[i];
    part[t] = s;
    __syncthreads();
    for (int off = 1; off < 256; off <<= 1) {
        int v = (t >= off) ? part[t - off] : 0;
        __syncthreads();
        part[t] += v;
        __syncthreads();
    }
    int run = (t == 0) ? 0 : part[t - 1];
    for (int i = lo; i < hi; ++i) { rowptr[i] = run; wpos[i] = run; run += cnt[i]; }
    if (t == 255) rowptr[NNODES] = part[255];
}

__global__ void fill_csr(const int* __restrict__ ei, int* __restrict__ wpos,
                         int* __restrict__ colsrc) {
    int e = blockIdx.x * 256 + threadIdx.x;
    if (e < NEDGES) {
        int d = ei[NEDGES + e];
        int slot = atomicAdd(&wpos[d], 1);
        colsrc[slot] = ei[e];            // store src node id
    }
}

// ------------------------------------------------- fused head weight (wl@wl2)
__global__ void fuse_wl(const float* __restrict__ wl, const float* __restrict__ bl,
                        const float* __restrict__ wl2, const float* __restrict__ bl2,
                        float* __restrict__ wf, float* __restrict__ bf) {
    int t = threadIdx.x;                 // 128 threads
    float s = 0.f;
    for (int j = 0; j < 128; ++j) s += wl[t * 128 + j] * wl2[j];
    wf[t] = s;
    if (t == 0) {
        float s2 = 0.f;
        for (int j = 0; j < 128; ++j) s2 += bl[j] * wl2[j];
        bf[0] = s2 + bl2[0];
    }
}

// ---------------------------------------------------------------- fused GEMM
// O[sel] = F @ W[sel] + b[sel] for sel in {Q,K,V,skip}; F is (NNODES x 128).
// Tile: 128 rows x 64 cols, K chunked by 32, reg-staged double-buffered A.
__global__ __launch_bounds__(256, 2)
void gemm_qkvs(const float* __restrict__ F,
               const float* __restrict__ wq, const float* __restrict__ bq,
               const float* __restrict__ wk, const float* __restrict__ bk,
               const float* __restrict__ wv, const float* __restrict__ bv,
               const float* __restrict__ wsk, const float* __restrict__ bsk,
               float* __restrict__ Q, float* __restrict__ Kp,
               float* __restrict__ V, float* __restrict__ H) {
    __shared__ __align__(16) float Bs[128][64];        // 32 KB (full K)
    __shared__ __align__(16) float As[2][32][132];     // 2 x 16.5 KB, transposed, padded
    const int tid = threadIdx.x;
    const int bn  = blockIdx.y;
    const int sel = bn >> 1;
    const int c0  = (bn & 1) * 64;
    const float* W    = sel == 0 ? wq : sel == 1 ? wk : sel == 2 ? wv : wsk;
    const float* bias = sel == 0 ? bq : sel == 1 ? bk : sel == 2 ? bv : bsk;
    float* O          = sel == 0 ? Q  : sel == 1 ? Kp : sel == 2 ? V  : H;

    {   // stage B slice (128 x 64) once
        int r  = tid >> 4;
        int cq = (tid & 15) * 4;
#pragma unroll
        for (int p = 0; p < 8; ++p)
            *(float4*)&Bs[r + p * 16][cq] = *(const float4*)&W[(r + p * 16) * 128 + c0 + cq];
    }
    const int m0 = blockIdx.x * 128;
    float4 areg[4];
    auto loadA = [&](int kc) {
#pragma unroll
        for (int p = 0; p < 4; ++p) {
            int idx = tid + p * 256;
            int row = idx >> 3;
            int kq  = (idx & 7) * 4;
            int gr  = m0 + row;
            areg[p] = (gr < NNODES) ? *(const float4*)&F[gr * 128 + kc * 32 + kq]
                                    : make_float4(0.f, 0.f, 0.f, 0.f);
        }
    };
    auto writeA = [&](int buf) {
#pragma unroll
        for (int p = 0; p < 4; ++p) {
            int idx = tid + p * 256;
            int row = idx >> 3;
            int kq  = (idx & 7) * 4;
            As[buf][kq + 0][row] = areg[p].x;
            As[buf][kq + 1][row] = areg[p].y;
            As[buf][kq + 2][row] = areg[p].z;
            As[buf][kq + 3][row] = areg[p].w;
        }
    };
    float acc[8][4] = {};
    const int tr = (tid >> 4) * 8;
    const int tc = (tid & 15) * 4;
    loadA(0);
    writeA(0);
    __syncthreads();
    for (int kc = 0; kc < 4; ++kc) {
        int buf = kc & 1;
        if (kc < 3) loadA(kc + 1);       // issue global loads early (T14 split)
#pragma unroll
        for (int k = 0; k < 32; ++k) {
            float4 a0 = *(const float4*)&As[buf][k][tr];
            float4 a1 = *(const float4*)&As[buf][k][tr + 4];
            float4 b  = *(const float4*)&Bs[kc * 32 + k][tc];
            float av[8] = {a0.x, a0.y, a0.z, a0.w, a1.x, a1.y, a1.z, a1.w};
            float bb[4] = {b.x, b.y, b.z, b.w};
#pragma unroll
            for (int i = 0; i < 8; ++i)
#pragma unroll
                for (int j = 0; j < 4; ++j) acc[i][j] += av[i] * bb[j];
        }
        if (kc < 3) writeA(buf ^ 1);     // write LDS late, after compute
        __syncthreads();
    }
    float4 bv4 = *(const float4*)&bias[c0 + tc];
#pragma unroll
    for (int i = 0; i < 8; ++i) {
        int gr = m0 + tr + i;
        if (gr < NNODES) {
            float4 o = make_float4(acc[i][0] + bv4.x, acc[i][1] + bv4.y,
                                   acc[i][2] + bv4.z, acc[i][3] + bv4.w);
            *(float4*)&O[gr * 128 + c0 + tc] = o;
        }
    }
}

// --------------------------------------------- per-dst-node online softmax agg
// block = 128 threads (channel c = tid; head = c>>5), one block per node.
// H holds the skip term on entry; on exit H = relu(skip + attn_msg).
__global__ __launch_bounds__(128)
void attn_agg(const float* __restrict__ Q, const float* __restrict__ K,
              const float* __restrict__ V, float* __restrict__ H,
              const int* __restrict__ rowptr, const int* __restrict__ colsrc) {
    const int n = blockIdx.x;
    const int c = threadIdx.x;
    const float q = Q[n * 128 + c] * 0.17677669529663687f;   // 1/sqrt(32) folded
    const int beg = rowptr[n], end = rowptr[n + 1];
    float m = -INFINITY, s = 0.f, acc = 0.f;
    float kN = 0.f, vN = 0.f;
    if (beg < end) {
        int s0 = colsrc[beg];
        kN = K[s0 * 128 + c];
        vN = V[s0 * 128 + c];
    }
    for (int i = beg; i < end; ++i) {
        float kc = kN, vc = vN;
        if (i + 1 < end) {               // prefetch next edge's K/V
            int s2 = colsrc[i + 1];
            kN = K[s2 * 128 + c];
            vN = V[s2 * 128 + c];
        }
        float p = q * kc;
#pragma unroll
        for (int off = 16; off > 0; off >>= 1) p += __shfl_xor(p, off, 32);
        float nm = fmaxf(m, p);
        float sc = __expf(m - nm);
        float w  = __expf(p - nm);
        s   = s * sc + w;
        acc = acc * sc + w * vc;
        m = nm;
    }
    float out = H[n * 128 + c];
    if (end > beg) out += acc / s;
    H[n * 128 + c] = fmaxf(out, 0.f);
}

// ------------------------------------------------------------- head + pooling
__global__ __launch_bounds__(256)
void pool_nodes(const float* __restrict__ H2, const float* __restrict__ wf,
                const float* __restrict__ bf, const int* __restrict__ batch,
                float* __restrict__ gsum, float* __restrict__ gcnt) {
    int node = blockIdx.x * 4 + (threadIdx.x >> 6);
    int lane = threadIdx.x & 63;
    if (node >= NNODES) return;
    float r = H2[node * 128 + lane] * wf[lane] +
              H2[node * 128 + 64 + lane] * wf[64 + lane];
#pragma unroll
    for (int off = 32; off > 0; off >>= 1) r += __shfl_xor(r, off, 64);
    if (lane == 0) {
        int g = batch[node];
        atomicAdd(&gsum[g], r + bf[0]);
        atomicAdd(&gcnt[g], 1.f);
    }
}

__global__ void finalize_pool(const float* __restrict__ gsum,
                              const float* __restrict__ gcnt, float* __restrict__ out) {
    int g = threadIdx.x;
    if (g < NGRAPHS) out[g] = gsum[g] / fmaxf(gcnt[g], 1.f);
}

// ---------------------------------------------------------------------- launch
extern "C" void kernel_launch(void* const* d_in, const int* in_sizes, int n_in,
                              void* d_out, int out_size, void* d_ws, size_t ws_size,
                              hipStream_t stream) {
    const float* x     = (const float*)d_in[0];
    const int*   ei    = (const int*)d_in[1];
    const int*   batch = (const int*)d_in[2];
    const float* wq1 = (const float*)d_in[3];  const float* bq1 = (const float*)d_in[4];
    const float* wk1 = (const float*)d_in[5];  const float* bk1 = (const float*)d_in[6];
    const float* wv1 = (const float*)d_in[7];  const float* bv1 = (const float*)d_in[8];
    const float* ws1 = (const float*)d_in[9];  const float* bs1 = (const float*)d_in[10];
    const float* wq2 = (const float*)d_in[11]; const float* bq2 = (const float*)d_in[12];
    const float* wk2 = (const float*)d_in[13]; const float* bk2 = (const float*)d_in[14];
    const float* wv2 = (const float*)d_in[15]; const float* bv2 = (const float*)d_in[16];
    const float* ws2 = (const float*)d_in[17]; const float* bs2 = (const float*)d_in[18];
    const float* wl  = (const float*)d_in[19]; const float* bl  = (const float*)d_in[20];
    const float* wl2 = (const float*)d_in[21]; const float* bl2 = (const float*)d_in[22];

    char* wsb = (char*)d_ws;
    size_t off = 0;
    auto carve = [&](size_t bytes) -> void* {
        void* p = wsb + off;
        off = (off + bytes + 255) & ~(size_t)255;
        return p;
    };
    const size_t NM = (size_t)NNODES * 128 * sizeof(float);   // 25.6 MB
    float* Q      = (float*)carve(NM);
    float* K      = (float*)carve(NM);
    float* V      = (float*)carve(NM);
    float* H1     = (float*)carve(NM);
    float* H2     = (float*)carve(NM);
    int*   rowptr = (int*)carve((NNODES + 1) * sizeof(int));
    int*   wpos   = (int*)carve(NNODES * sizeof(int));
    int*   cnt    = (int*)carve(NNODES * sizeof(int));
    int*   colsrc = (int*)carve(NEDGES * sizeof(int));
    float* wf     = (float*)carve(129 * sizeof(float));  // 128 fused weights + bias
    float* bf     = wf + 128;
    float* gsum   = (float*)carve(2 * NGRAPHS * sizeof(float));
    float* gcnt   = gsum + NGRAPHS;

    hipMemsetAsync(cnt, 0, NNODES * sizeof(int), stream);
    hipMemsetAsync(gsum, 0, 2 * NGRAPHS * sizeof(float), stream);

    count_edges<<<(NEDGES + 255) / 256, 256, 0, stream>>>(ei, cnt);
    scan_counts<<<1, 256, 0, stream>>>(cnt, rowptr, wpos);
    fill_csr<<<(NEDGES + 255) / 256, 256, 0, stream>>>(ei, wpos, colsrc);
    fuse_wl<<<1, 128, 0, stream>>>(wl, bl, wl2, bl2, wf, bf);

    dim3 ggrid((NNODES + 127) / 128, 8);
    // layer 1
    gemm_qkvs<<<ggrid, 256, 0, stream>>>(x, wq1, bq1, wk1, bk1, wv1, bv1, ws1, bs1,
                                         Q, K, V, H1);
    attn_agg<<<NNODES, 128, 0, stream>>>(Q, K, V, H1, rowptr, colsrc);
    // layer 2
    gemm_qkvs<<<ggrid, 256, 0, stream>>>(H1, wq2, bq2, wk2, bk2, wv2, bv2, ws2, bs2,
                                         Q, K, V, H2);
    attn_agg<<<NNODES, 128, 0, stream>>>(Q, K, V, H2, rowptr, colsrc);
    // fused head + mean pool
    pool_nodes<<<(NNODES + 3) / 4, 256, 0, stream>>>(H2, wf, bf, batch, gsum, gcnt);
    finalize_pool<<<1, 128, 0, stream>>>(gsum, gcnt, (float*)d_out);
}